// Round 15
// baseline (580.993 us; speedup 1.0000x reference)
//
#include <hip/hip_runtime.h>
#include <math.h>
#include <stdint.h>

#define LSEQ 4096
#define NCHUNK 4
#define TC 1024  // LSEQ / NCHUNK

#define AS1 __attribute__((address_space(1)))
#define AS3 __attribute__((address_space(3)))
__device__ __forceinline__ void gload_lds16(const void* g, void* l) {
  __builtin_amdgcn_global_load_lds((const AS1 unsigned int*)g,
                                   (AS3 unsigned int*)l, 16, 0, 0);
}

// raw v_exp_f32 (exp2). libm exp2f carries denorm-range fixup (~6 VALU);
// results below 2^-126 flush to zero, irrelevant at our 2.4e-6 threshold.
#define EXP2R(X) __builtin_amdgcn_exp2f(X)
#define LOG2E 1.44269504f

// ---------------- router: conv3x3 + relu + pooled sums ----------------
__global__ __launch_bounds__(256) void k_router_conv(
    const float* __restrict__ x, const float* __restrict__ rcw,
    const float* __restrict__ rcb, float* __restrict__ rpool) {
  int bid = blockIdx.x;
  int ocq = bid & 3;
  int h = (bid >> 2) & 63;
  int b = bid >> 8;
  __shared__ float xs[16][3][66];
  __shared__ float wl[16][145];
  int tid = threadIdx.x;
  int ocl = tid & 15;
  int oc = ocq * 16 + ocl;
  int w0 = (tid >> 4) * 4;
  if (tid < 96) {
    int ic = tid / 6, rr = tid % 6;
    int row = rr >> 1, edge = (rr & 1) ? 65 : 0;
    xs[ic][row][edge] = 0.f;
  }
  float acc[4] = {};
  for (int cc = 0; cc < 8; ++cc) {
    __syncthreads();
#pragma unroll
    for (int i = 0; i < 12; ++i) {
      int f = tid + i * 256;
      int ic = f / 192, rem = f % 192;
      int row = rem / 64, w = rem & 63;
      int hh = h - 1 + row;
      float v = 0.f;
      if (hh >= 0 && hh < 64)
        v = x[((size_t)(b * 128 + cc * 16 + ic) * 64 + hh) * 64 + w];
      xs[ic][row][w + 1] = v;
    }
    for (int f = tid; f < 2304; f += 256) {
      int o = f / 144, r = f % 144;
      wl[o][r] = rcw[(size_t)(ocq * 16 + o) * 1152 + cc * 144 + r];
    }
    __syncthreads();
    for (int ic = 0; ic < 16; ++ic) {
#pragma unroll
      for (int kh = 0; kh < 3; ++kh) {
        float xv[6];
#pragma unroll
        for (int j = 0; j < 6; ++j) xv[j] = xs[ic][kh][w0 + j];
        float w_0 = wl[ocl][ic * 9 + kh * 3 + 0];
        float w_1 = wl[ocl][ic * 9 + kh * 3 + 1];
        float w_2 = wl[ocl][ic * 9 + kh * 3 + 2];
#pragma unroll
        for (int i = 0; i < 4; ++i)
          acc[i] += w_0 * xv[i] + w_1 * xv[i + 1] + w_2 * xv[i + 2];
      }
    }
  }
  float cbv = rcb[oc];
  float t = 0.f;
#pragma unroll
  for (int i = 0; i < 4; ++i) t += fmaxf(acc[i] + cbv, 0.f);
  t += __shfl_xor(t, 16);
  t += __shfl_xor(t, 32);
  if ((tid & 63) < 16) atomicAdd(rpool + b * 64 + oc, t);
}

__global__ __launch_bounds__(64) void k_router_softmax(
    const float* __restrict__ rpool, const float* __restrict__ rlw,
    const float* __restrict__ rlb, float* __restrict__ rw) {
  int t = threadIdx.x;
  __shared__ float logits[2][3];
  for (int b = 0; b < 2; ++b) {
    float p = rpool[b * 64 + t] * (1.0f / 4096.0f);
    for (int e = 0; e < 3; ++e) {
      float v = p * rlw[e * 64 + t];
      for (int off = 32; off; off >>= 1) v += __shfl_xor(v, off);
      if (t == 0) logits[b][e] = v + rlb[e];
    }
  }
  __syncthreads();
  if (t == 0) {
    for (int b = 0; b < 2; ++b) {
      float m = fmaxf(fmaxf(logits[b][0], logits[b][1]), logits[b][2]);
      float e0 = expf(logits[b][0] - m), e1 = expf(logits[b][1] - m),
            e2 = expf(logits[b][2] - m);
      float s = e0 + e1 + e2;
      rw[b * 3 + 0] = e0 / s;
      rw[b * 3 + 1] = e1 / s;
      rw[b * 3 + 2] = e2 / s;
    }
  }
}

// ---------------- fused out-proj weights: WF[e] = fw @ outw[e] ----------------
__global__ __launch_bounds__(256) void k_wfuse(
    const float* __restrict__ fw, const float* __restrict__ outw,
    float* __restrict__ wf) {
  int e = blockIdx.x >> 7;
  int co = blockIdx.x & 127;
  int k = threadIdx.x;
  float acc = 0.f;
  const float* fwr = fw + (size_t)co * 128;
  const float* ob = outw + (size_t)e * 128 * 256 + k;
#pragma unroll 8
  for (int m = 0; m < 128; ++m) acc = fmaf(fwr[m], ob[(size_t)m * 256], acc);
  wf[((size_t)e * 128 + co) * 256 + k] = acc;
}

// ---------------- in-projection GEMM: xr[e,b,l,0:512] ----------------
__global__ __launch_bounds__(256) void k_gemm_in(
    const float* __restrict__ x, const float* __restrict__ inw,
    float* __restrict__ xr) {
  int eb = blockIdx.y;
  int e = eb >> 1, b = eb & 1;
  int lt = blockIdx.x >> 3;
  int jt = blockIdx.x & 7;
  int l0 = lt * 128, j0 = jt * 64;
  __shared__ float xt[16][128];
  __shared__ float wt[16][64];
  int tid = threadIdx.x;
  int jj = (tid & 15) * 4;
  int lr = (tid >> 4) * 8;
  float acc[8][4] = {};
  const float* xb = x + (size_t)b * 128 * 4096;
  const float* wb = inw + (size_t)e * 512 * 128;
  for (int c0 = 0; c0 < 128; c0 += 16) {
    __syncthreads();
#pragma unroll
    for (int i = 0; i < 2; ++i) {
      int f = tid + i * 256;
      int c = f >> 5;
      int lp = (f & 31) * 4;
      float4 v = *(const float4*)(xb + (size_t)(c0 + c) * 4096 + l0 + lp);
      *(float4*)(&xt[c][lp]) = v;
    }
    {
      int j = tid >> 2;
      int kk = (tid & 3) * 4;
      float4 v = *(const float4*)(wb + (size_t)(j0 + j) * 128 + c0 + kk);
      wt[kk + 0][j] = v.x; wt[kk + 1][j] = v.y;
      wt[kk + 2][j] = v.z; wt[kk + 3][j] = v.w;
    }
    __syncthreads();
#pragma unroll
    for (int k = 0; k < 16; ++k) {
      float4 bv = *(const float4*)(&wt[k][jj]);
      float4 a0 = *(const float4*)(&xt[k][lr]);
      float4 a1 = *(const float4*)(&xt[k][lr + 4]);
      float av[8] = {a0.x, a0.y, a0.z, a0.w, a1.x, a1.y, a1.z, a1.w};
#pragma unroll
      for (int i = 0; i < 8; ++i) {
        acc[i][0] = fmaf(av[i], bv.x, acc[i][0]);
        acc[i][1] = fmaf(av[i], bv.y, acc[i][1]);
        acc[i][2] = fmaf(av[i], bv.z, acc[i][2]);
        acc[i][3] = fmaf(av[i], bv.w, acc[i][3]);
      }
    }
  }
  float* out = xr + (size_t)eb * 4096 * 512;
#pragma unroll
  for (int i = 0; i < 8; ++i) {
    float4 v = {acc[i][0], acc[i][1], acc[i][2], acc[i][3]};
    *(float4*)(out + (size_t)(l0 + lr + i) * 512 + j0 + jj) = v;
  }
}

// ---------------- depthwise causal conv1d + silu (16 t per block) ----------------
__global__ __launch_bounds__(256) void k_conv1d(
    const float* __restrict__ xr, const float* __restrict__ cw,
    const float* __restrict__ cb, float* __restrict__ xact) {
  int eb = blockIdx.y;
  int e = eb >> 1;
  int l0 = blockIdx.x * 16;
  int d = threadIdx.x;
  const float* w = cw + (size_t)(e * 256 + d) * 4;
  float w0_ = w[0], w1_ = w[1], w2_ = w[2], w3_ = w[3];
  float bias = cb[e * 256 + d];
  const float* xin = xr + (size_t)eb * 4096 * 512 + d;
  float* xo = xact + (size_t)eb * 4096 * 256 + d;
  float xm3 = (l0 >= 3) ? xin[(size_t)(l0 - 3) * 512] : 0.f;
  float xm2 = (l0 >= 2) ? xin[(size_t)(l0 - 2) * 512] : 0.f;
  float xm1 = (l0 >= 1) ? xin[(size_t)(l0 - 1) * 512] : 0.f;
#pragma unroll
  for (int i = 0; i < 16; ++i) {
    float xc = xin[(size_t)(l0 + i) * 512];
    float v = bias + w0_ * xm3 + w1_ * xm2 + w2_ * xm1 + w3_ * xc;
    xo[(size_t)(l0 + i) * 256] = v / (1.0f + expf(-v));
    xm3 = xm2; xm2 = xm1; xm1 = xc;
  }
}

// ---------------- xproj GEMM: dbl[e,b,l,0:136] ----------------
__global__ __launch_bounds__(256) void k_gemm_xproj(
    const float* __restrict__ xact, const float* __restrict__ xpw,
    float* __restrict__ dbl) {
  int eb = blockIdx.y;
  int e = eb >> 1;
  int lt = blockIdx.x / 3, jt = blockIdx.x % 3;
  int l0 = lt * 128, j0 = jt * 64;
  __shared__ float at[16][128];
  __shared__ float wt[16][64];
  int tid = threadIdx.x;
  int jj = (tid & 15) * 4;
  int lr = (tid >> 4) * 8;
  float acc[8][4] = {};
  const float* ab = xact + (size_t)eb * 4096 * 256;
  const float* wb = xpw + (size_t)e * 136 * 256;
  for (int k0 = 0; k0 < 256; k0 += 16) {
    __syncthreads();
#pragma unroll
    for (int i = 0; i < 2; ++i) {
      int f = tid + i * 256;
      int l = f >> 2, kq = (f & 3) * 4;
      float4 v = *(const float4*)(ab + (size_t)(l0 + l) * 256 + k0 + kq);
      at[kq + 0][l] = v.x; at[kq + 1][l] = v.y;
      at[kq + 2][l] = v.z; at[kq + 3][l] = v.w;
    }
    {
      int j = tid >> 2, kk = (tid & 3) * 4;
      float4 v = {0, 0, 0, 0};
      if (j0 + j < 136)
        v = *(const float4*)(wb + (size_t)(j0 + j) * 256 + k0 + kk);
      wt[kk + 0][j] = v.x; wt[kk + 1][j] = v.y;
      wt[kk + 2][j] = v.z; wt[kk + 3][j] = v.w;
    }
    __syncthreads();
#pragma unroll
    for (int k = 0; k < 16; ++k) {
      float4 bv = *(const float4*)(&wt[k][jj]);
      float4 a0 = *(const float4*)(&at[k][lr]);
      float4 a1 = *(const float4*)(&at[k][lr + 4]);
      float av[8] = {a0.x, a0.y, a0.z, a0.w, a1.x, a1.y, a1.z, a1.w};
#pragma unroll
      for (int i = 0; i < 8; ++i) {
        acc[i][0] = fmaf(av[i], bv.x, acc[i][0]);
        acc[i][1] = fmaf(av[i], bv.y, acc[i][1]);
        acc[i][2] = fmaf(av[i], bv.z, acc[i][2]);
        acc[i][3] = fmaf(av[i], bv.w, acc[i][3]);
      }
    }
  }
  float* ob = dbl + (size_t)eb * 4096 * 136;
  for (int i = 0; i < 8; ++i)
    for (int q = 0; q < 4; ++q) {
      int j = j0 + jj + q;
      if (j < 136) ob[(size_t)(l0 + lr + i) * 136 + j] = acc[i][q];
    }
}

// ---------------- delta pass (32 t per block) ----------------
__global__ __launch_bounds__(256) void k_delta(
    const float* __restrict__ dbl, const float* __restrict__ dtw,
    const float* __restrict__ dtb, const float* __restrict__ xact,
    float* __restrict__ dd) {
  int eb = blockIdx.y;
  int e = eb >> 1;
  int t0 = blockIdx.x * 32;
  int d = threadIdx.x;
  __shared__ float dt8[32][8];
  {
    int f = threadIdx.x;
    if (f < 256) {
      int l = f >> 3, r = f & 7;
      dt8[l][r] = dbl[(size_t)eb * 4096 * 136 + (size_t)(t0 + l) * 136 + r];
    }
  }
  __syncthreads();
  float w[8];
#pragma unroll
  for (int r = 0; r < 8; ++r) w[r] = dtw[(size_t)(e * 256 + d) * 8 + r];
  float bias = dtb[e * 256 + d];
  const float* xa = xact + (size_t)eb * 4096 * 256 + d;
  float4* out = (float4*)dd + (size_t)(eb * 256 + d) * 2048 + (t0 >> 1);
  for (int i = 0; i < 32; i += 2) {
    float v0 = bias, v1 = bias;
#pragma unroll
    for (int r = 0; r < 8; ++r) {
      v0 += dt8[i][r] * w[r];
      v1 += dt8[i + 1][r] * w[r];
    }
    float de0 = fmaxf(v0, 0.f) + log1pf(expf(-fabsf(v0)));
    float de1 = fmaxf(v1, 0.f) + log1pf(expf(-fabsf(v1)));
    float u0 = xa[(size_t)(t0 + i) * 256];
    float u1 = xa[(size_t)(t0 + i + 1) * 256];
    float4 o = {de0, de0 * u0, de1, de1 * u1};
    out[i >> 1] = o;
  }
}

// ---------------- chunked selective scan (R11 structure, NCHUNK=4) ----------------
#define S1STEP(DVX, DVY, ROW)                    \
  {                                              \
    float Bn = sB[cur][ROW][lane];               \
    h = fmaf(EXP2R((DVX)*An2), h, (DVY)*Bn);     \
    sdel += (DVX);                               \
  }
#define S1HALF(R0, R1, R2, R3, ROFF)             \
  {                                              \
    S1STEP(R0.x, R0.y, (ROFF) + 0)               \
    S1STEP(R0.z, R0.w, (ROFF) + 1)               \
    S1STEP(R1.x, R1.y, (ROFF) + 2)               \
    S1STEP(R1.z, R1.w, (ROFF) + 3)               \
    S1STEP(R2.x, R2.y, (ROFF) + 4)               \
    S1STEP(R2.z, R2.w, (ROFF) + 5)               \
    S1STEP(R3.x, R3.y, (ROFF) + 6)               \
    S1STEP(R3.z, R3.w, (ROFF) + 7)               \
  }

// pass 1: per (eb,d,chunk c<3): local scan h=0 -> h_end; prod = exp2(An2*sum(delta))
__global__ __launch_bounds__(256, 6) void k_scan1(
    const float* __restrict__ dbl, const float* __restrict__ dd,
    const float* __restrict__ alog, float* __restrict__ prd,
    float* __restrict__ hend) {
  __shared__ float sB[2][16][64];
  int eb = blockIdx.y;
  int e = eb >> 1;
  int c = blockIdx.x >> 6;
  int dgrp = blockIdx.x & 63;
  int wid = threadIdx.x >> 6, lane = threadIdx.x & 63;
  int d = dgrp * 4 + wid;
  float An2 = -__expf(alog[((size_t)e * 256 + d) * 64 + lane]) * LOG2E;
  const float2* ddp = (const float2*)dd + ((size_t)eb * 256 + d) * 4096;
  {
    uint64_t a = (uint64_t)ddp;
    uint32_t lo = __builtin_amdgcn_readfirstlane((int)(uint32_t)a);
    uint32_t hi = __builtin_amdgcn_readfirstlane((int)(uint32_t)(a >> 32));
    ddp = (const float2*)(((uint64_t)hi << 32) | (uint64_t)lo);
  }
  const float4* dq = (const float4*)ddp;
  const float* dblb = dbl + (size_t)eb * 4096 * 136;
  int t0 = c * TC;
  int qb = t0 >> 1;
  int srow = 4 * wid + (lane >> 4);
  int scol = (lane & 15) * 4;
  float h = 0.f, sdel = 0.f;
  float4 ra0 = dq[qb + 0], ra1 = dq[qb + 1], ra2 = dq[qb + 2],
         ra3 = dq[qb + 3];
  float4 rb0, rb1, rb2, rb3;
  gload_lds16(dblb + (size_t)(t0 + srow) * 136 + 8 + scol, &sB[0][4 * wid][0]);
  __syncthreads();
  for (int sb = 0; sb < 64; ++sb) {
    int cur = sb & 1;
    if (sb + 1 < 64)
      gload_lds16(dblb + (size_t)(t0 + (sb + 1) * 16 + srow) * 136 + 8 + scol,
                  &sB[cur ^ 1][4 * wid][0]);
    int qA = qb + sb * 8;
    rb0 = dq[qA + 4]; rb1 = dq[qA + 5]; rb2 = dq[qA + 6]; rb3 = dq[qA + 7];
    S1HALF(ra0, ra1, ra2, ra3, 0)
    ra0 = dq[qA + 8]; ra1 = dq[qA + 9]; ra2 = dq[qA + 10]; ra3 = dq[qA + 11];
    S1HALF(rb0, rb1, rb2, rb3, 8)
    __syncthreads();
  }
  size_t o = (((size_t)eb * 256 + d) * NCHUNK + c) * 64 + lane;
  prd[o] = EXP2R(An2 * sdel);
  hend[o] = h;
}

// pass 2: sequential combine over chunks -> h_init per chunk
__global__ __launch_bounds__(256) void k_scan2(
    const float* __restrict__ prd, const float* __restrict__ hend,
    float* __restrict__ hinit) {
  int w = blockIdx.x * 4 + (threadIdx.x >> 6);
  int lane = threadIdx.x & 63;
  size_t base = (size_t)w * NCHUNK * 64 + lane;
  float h = 0.f;
  hinit[base] = 0.f;
#pragma unroll
  for (int c = 1; c < NCHUNK; ++c) {
    h = fmaf(prd[base + (c - 1) * 64], h, hend[base + (c - 1) * 64]);
    hinit[base + c * 64] = h;
  }
}

#define S3STEP(DVX, DVY, ROW, JJ)                  \
  {                                                \
    float Bn = sBC[cur][ROW][lane];                \
    float Cn = sBC[cur][ROW][64 + lane];           \
    h = fmaf(EXP2R((DVX)*An2), h, (DVY)*Bn);       \
    P[wid][JJ][lane] = h * Cn;                     \
  }
#define S3HALF(R0, R1, R2, R3, ROFF, TB)           \
  {                                                \
    S3STEP(R0.x, R0.y, (ROFF) + 0, 0)              \
    S3STEP(R0.z, R0.w, (ROFF) + 1, 1)              \
    S3STEP(R1.x, R1.y, (ROFF) + 2, 2)              \
    S3STEP(R1.z, R1.w, (ROFF) + 3, 3)              \
    S3STEP(R2.x, R2.y, (ROFF) + 4, 4)              \
    S3STEP(R2.z, R2.w, (ROFF) + 5, 5)              \
    S3STEP(R3.x, R3.y, (ROFF) + 6, 6)              \
    S3STEP(R3.z, R3.w, (ROFF) + 7, 7)              \
    float acc_ = 0.f;                              \
    _Pragma("unroll")                              \
    for (int k2 = 0; k2 < 8; ++k2)                 \
      acc_ += P[wid][r][q * 8 + k2];               \
    acc_ += __shfl_xor(acc_, 8);                   \
    acc_ += __shfl_xor(acc_, 16);                  \
    acc_ += __shfl_xor(acc_, 32);                  \
    if (lane < 8) yout[(TB) + r] = acc_;           \
  }

// pass 3: local scan from h_init; 16-t B+C staging subblocks (24.7 KB LDS),
// ddp prefetched one 8-t block ahead; per-wave deferred LDS reduce each 8 t.
__global__ __launch_bounds__(256, 6) void k_scan3(
    const float* __restrict__ dbl, const float* __restrict__ dd,
    const float* __restrict__ alog, const float* __restrict__ hinit,
    float* __restrict__ ytr) {
  __shared__ float sBC[2][16][128];
  __shared__ float P[4][8][65];
  int eb = blockIdx.y;
  int e = eb >> 1;
  int c = blockIdx.x >> 6;
  int dgrp = blockIdx.x & 63;
  int wid = threadIdx.x >> 6, lane = threadIdx.x & 63;
  int d = dgrp * 4 + wid;
  float An2 = -__expf(alog[((size_t)e * 256 + d) * 64 + lane]) * LOG2E;
  const float2* ddp = (const float2*)dd + ((size_t)eb * 256 + d) * 4096;
  {
    uint64_t a = (uint64_t)ddp;
    uint32_t lo = __builtin_amdgcn_readfirstlane((int)(uint32_t)a);
    uint32_t hi = __builtin_amdgcn_readfirstlane((int)(uint32_t)(a >> 32));
    ddp = (const float2*)(((uint64_t)hi << 32) | (uint64_t)lo);
  }
  const float4* dq = (const float4*)ddp;
  const float* dblb = dbl + (size_t)eb * 4096 * 136;
  int t0 = c * TC;
  int qb = t0 >> 1;
  int scol = (lane & 31) * 4;
  int srow0 = 4 * wid + (lane >> 5);
  float h = hinit[(((size_t)eb * 256 + d) * NCHUNK + c) * 64 + lane];
  float* yout = ytr + ((size_t)eb * 256 + d) * 4096;
  int r = lane & 7, q = lane >> 3;
  float4 ra0 = dq[qb + 0], ra1 = dq[qb + 1], ra2 = dq[qb + 2],
         ra3 = dq[qb + 3];
  float4 rb0, rb1, rb2, rb3;
  gload_lds16(dblb + (size_t)(t0 + srow0) * 136 + 8 + scol,
              &sBC[0][4 * wid][0]);
  gload_lds16(dblb + (size_t)(t0 + srow0 + 2) * 136 + 8 + scol,
              &sBC[0][4 * wid + 2][0]);
  __syncthreads();
  for (int sb = 0; sb < 64; ++sb) {
    int cur = sb & 1;
    if (sb + 1 < 64) {
      int tN = t0 + (sb + 1) * 16;
      gload_lds16(dblb + (size_t)(tN + srow0) * 136 + 8 + scol,
                  &sBC[cur ^ 1][4 * wid][0]);
      gload_lds16(dblb + (size_t)(tN + srow0 + 2) * 136 + 8 + scol,
                  &sBC[cur ^ 1][4 * wid + 2][0]);
    }
    int qA = qb + sb * 8;
    int tA = t0 + sb * 16;
    rb0 = dq[qA + 4]; rb1 = dq[qA + 5]; rb2 = dq[qA + 6]; rb3 = dq[qA + 7];
    S3HALF(ra0, ra1, ra2, ra3, 0, tA)
    ra0 = dq[qA + 8]; ra1 = dq[qA + 9]; ra2 = dq[qA + 10]; ra3 = dq[qA + 11];
    S3HALF(rb0, rb1, rb2, rb3, 8, tA + 8)
    __syncthreads();
  }
}

// ---------------- y fuse ----------------
__global__ __launch_bounds__(256) void k_yfuse(
    const float* __restrict__ ytr, const float* __restrict__ xact,
    const float* __restrict__ xr, const float* __restrict__ Dw,
    float* __restrict__ yf) {
  int eb = blockIdx.y;
  int e = eb >> 1;
  int dti = blockIdx.x >> 6, tti = blockIdx.x & 63;
  int d0 = dti * 64, t0 = tti * 64;
  __shared__ float sp[64][65];
  __shared__ float sq[64][65];
  int tid = threadIdx.x;
  int j = tid & 63;
  int r0 = tid >> 6;
  float Dj = Dw[e * 256 + d0 + j];
  const float* xab = xact + (size_t)eb * 4096 * 256;
  const float* xrb = xr + (size_t)eb * 4096 * 512;
#pragma unroll
  for (int it = 0; it < 16; ++it) {
    int r = r0 + it * 4;
    float xa = xab[(size_t)(t0 + r) * 256 + d0 + j];
    float rs = xrb[(size_t)(t0 + r) * 512 + 256 + d0 + j];
    float pch = rs / (1.0f + expf(-rs));
    sp[r][j] = pch;
    sq[r][j] = xa * Dj * pch;
  }
  __syncthreads();
#pragma unroll
  for (int it = 0; it < 16; ++it) {
    int ddr = r0 + it * 4;
    size_t idx = ((size_t)eb * 256 + d0 + ddr) * 4096 + t0 + j;
    float y = ytr[idx];
    yf[idx] = y * sp[j][ddr] + sq[j][ddr];
  }
}

// ---------------- fused out-proj + expert-mix + fusion GEMM -> d_out ----------------
// 32x64 tiles: grid (256, 2) = 512 blocks (2/CU; the 64x64 tiling was 1/CU).
__global__ __launch_bounds__(256) void k_gemm_out2(
    const float* __restrict__ yf, const float* __restrict__ wf,
    const float* __restrict__ rw, const float* __restrict__ fb,
    float* __restrict__ out) {
  int b = blockIdx.y;
  int tt = blockIdx.x >> 1;
  int ct = blockIdx.x & 1;
  int t0 = tt * 32, c0 = ct * 64;
  __shared__ float at[16][34];
  __shared__ float wt[16][64];
  int tid = threadIdx.x;
  int c4 = (tid & 15) * 4;
  int t2 = (tid >> 4) * 2;
  float acc[2][4] = {};
  for (int e = 0; e < 3; ++e) {
    float wbe = rw[b * 3 + e];
    const float* ab = yf + (size_t)(e * 2 + b) * 256 * 4096;
    const float* wb = wf + (size_t)e * 128 * 256;
    for (int k0 = 0; k0 < 256; k0 += 16) {
      __syncthreads();
      {
        int f = tid;
        for (int i = 0; i < 2; ++i, f += 256) {
          int t = f & 31, k = f >> 5;
          at[k][t] = ab[(size_t)(k0 + k) * 4096 + t0 + t];
        }
        int jc = tid >> 2, kk = (tid & 3) * 4;
        float4 v = *(const float4*)(wb + (size_t)(c0 + jc) * 256 + k0 + kk);
        wt[kk + 0][jc] = v.x * wbe; wt[kk + 1][jc] = v.y * wbe;
        wt[kk + 2][jc] = v.z * wbe; wt[kk + 3][jc] = v.w * wbe;
      }
      __syncthreads();
#pragma unroll
      for (int k = 0; k < 16; ++k) {
        float4 bv = *(const float4*)(&wt[k][c4]);
        float a0 = at[k][t2], a1 = at[k][t2 + 1];
        acc[0][0] = fmaf(a0, bv.x, acc[0][0]);
        acc[0][1] = fmaf(a0, bv.y, acc[0][1]);
        acc[0][2] = fmaf(a0, bv.z, acc[0][2]);
        acc[0][3] = fmaf(a0, bv.w, acc[0][3]);
        acc[1][0] = fmaf(a1, bv.x, acc[1][0]);
        acc[1][1] = fmaf(a1, bv.y, acc[1][1]);
        acc[1][2] = fmaf(a1, bv.z, acc[1][2]);
        acc[1][3] = fmaf(a1, bv.w, acc[1][3]);
      }
    }
  }
#pragma unroll
  for (int o = 0; o < 4; ++o) {
    float bias = fb[c0 + c4 + o];
    float2 v = {acc[0][o] + bias, acc[1][o] + bias};
    *(float2*)(out + ((size_t)(b * 128 + c0 + c4 + o)) * 4096 + t0 + t2) = v;
  }
}

extern "C" void kernel_launch(void* const* d_in, const int* in_sizes, int n_in,
                              void* d_out, int out_size, void* d_ws,
                              size_t ws_size, hipStream_t stream) {
  const float* x    = (const float*)d_in[0];
  const float* inw  = (const float*)d_in[1];
  const float* cw   = (const float*)d_in[2];
  const float* cb   = (const float*)d_in[3];
  const float* xpw  = (const float*)d_in[4];
  const float* dtw  = (const float*)d_in[5];
  const float* dtb  = (const float*)d_in[6];
  const float* alog = (const float*)d_in[7];
  const float* Dw   = (const float*)d_in[8];
  const float* outw = (const float*)d_in[9];
  const float* rcw  = (const float*)d_in[10];
  const float* rcb  = (const float*)d_in[11];
  const float* rlw  = (const float*)d_in[12];
  const float* rlb  = (const float*)d_in[13];
  const float* fw   = (const float*)d_in[14];
  const float* fb   = (const float*)d_in[15];

  float* ws = (float*)d_ws;
  float* XR    = ws;                 // 12,582,912
  float* XACT  = ws + 12582912;      // 6,291,456
  float* DBL   = ws + 18874368;      // 3,342,336
  float* DD    = ws + 22216704;      // 12,582,912 (also reused as YF)
  float* YTR   = ws + 34799616;      // 6,291,456
  float* MIX   = ws + 41091072;      // 1,048,576 (scratch region)
  float* RPOOL = ws + 42139648;      // 128
  float* RW    = ws + 42139776;      // 8
  float* YF    = DD;
  float* PRD   = YTR;
  float* HEND  = YTR + 393216;
  float* HINIT = MIX;
  float* WF    = MIX + 786432;

  if (ws_size < (size_t)42139784 * sizeof(float)) return;

  hipMemsetAsync(RPOOL, 0, 128 * sizeof(float), stream);
  k_router_conv<<<512, 256, 0, stream>>>(x, rcw, rcb, RPOOL);
  k_router_softmax<<<1, 64, 0, stream>>>(RPOOL, rlw, rlb, RW);
  k_wfuse<<<384, 256, 0, stream>>>(fw, outw, WF);
  k_gemm_in<<<dim3(256, 6), 256, 0, stream>>>(x, inw, XR);
  k_conv1d<<<dim3(256, 6), 256, 0, stream>>>(XR, cw, cb, XACT);
  k_gemm_xproj<<<dim3(96, 6), 256, 0, stream>>>(XACT, xpw, DBL);
  k_delta<<<dim3(128, 6), 256, 0, stream>>>(DBL, dtw, dtb, XACT, DD);
  k_scan1<<<dim3(64 * 3, 6), 256, 0, stream>>>(DBL, DD, alog, PRD, HEND);
  k_scan2<<<384, 256, 0, stream>>>(PRD, HEND, HINIT);
  k_scan3<<<dim3(64 * NCHUNK, 6), 256, 0, stream>>>(DBL, DD, alog, HINIT, YTR);
  k_yfuse<<<dim3(256, 6), 256, 0, stream>>>(YTR, XACT, XR, Dw, YF);
  k_gemm_out2<<<dim3(256, 2), 256, 0, stream>>>(YF, WF, RW, fb,
                                                (float*)d_out);
}

// Round 16
// 575.957 us; speedup vs baseline: 1.0087x; 1.0087x over previous
//
#include <hip/hip_runtime.h>
#include <math.h>
#include <stdint.h>

#define LSEQ 4096
#define NCHUNK 8
#define TC 512  // LSEQ / NCHUNK

#define AS1 __attribute__((address_space(1)))
#define AS3 __attribute__((address_space(3)))
__device__ __forceinline__ void gload_lds16(const void* g, void* l) {
  __builtin_amdgcn_global_load_lds((const AS1 unsigned int*)g,
                                   (AS3 unsigned int*)l, 16, 0, 0);
}

// raw v_exp_f32 (exp2). libm exp2f carries denorm-range fixup (~6 VALU);
// results below 2^-126 flush to zero, irrelevant at our 2.4e-6 threshold.
#define EXP2R(X) __builtin_amdgcn_exp2f(X)
#define LOG2E 1.44269504f

// ---------------- router: conv3x3 + relu + pooled sums ----------------
__global__ __launch_bounds__(256) void k_router_conv(
    const float* __restrict__ x, const float* __restrict__ rcw,
    const float* __restrict__ rcb, float* __restrict__ rpool) {
  int bid = blockIdx.x;
  int ocq = bid & 3;
  int h = (bid >> 2) & 63;
  int b = bid >> 8;
  __shared__ float xs[16][3][66];
  __shared__ float wl[16][145];
  int tid = threadIdx.x;
  int ocl = tid & 15;
  int oc = ocq * 16 + ocl;
  int w0 = (tid >> 4) * 4;
  if (tid < 96) {
    int ic = tid / 6, rr = tid % 6;
    int row = rr >> 1, edge = (rr & 1) ? 65 : 0;
    xs[ic][row][edge] = 0.f;
  }
  float acc[4] = {};
  for (int cc = 0; cc < 8; ++cc) {
    __syncthreads();
#pragma unroll
    for (int i = 0; i < 12; ++i) {
      int f = tid + i * 256;
      int ic = f / 192, rem = f % 192;
      int row = rem / 64, w = rem & 63;
      int hh = h - 1 + row;
      float v = 0.f;
      if (hh >= 0 && hh < 64)
        v = x[((size_t)(b * 128 + cc * 16 + ic) * 64 + hh) * 64 + w];
      xs[ic][row][w + 1] = v;
    }
    for (int f = tid; f < 2304; f += 256) {
      int o = f / 144, r = f % 144;
      wl[o][r] = rcw[(size_t)(ocq * 16 + o) * 1152 + cc * 144 + r];
    }
    __syncthreads();
    for (int ic = 0; ic < 16; ++ic) {
#pragma unroll
      for (int kh = 0; kh < 3; ++kh) {
        float xv[6];
#pragma unroll
        for (int j = 0; j < 6; ++j) xv[j] = xs[ic][kh][w0 + j];
        float w_0 = wl[ocl][ic * 9 + kh * 3 + 0];
        float w_1 = wl[ocl][ic * 9 + kh * 3 + 1];
        float w_2 = wl[ocl][ic * 9 + kh * 3 + 2];
#pragma unroll
        for (int i = 0; i < 4; ++i)
          acc[i] += w_0 * xv[i] + w_1 * xv[i + 1] + w_2 * xv[i + 2];
      }
    }
  }
  float cbv = rcb[oc];
  float t = 0.f;
#pragma unroll
  for (int i = 0; i < 4; ++i) t += fmaxf(acc[i] + cbv, 0.f);
  t += __shfl_xor(t, 16);
  t += __shfl_xor(t, 32);
  if ((tid & 63) < 16) atomicAdd(rpool + b * 64 + oc, t);
}

__global__ __launch_bounds__(64) void k_router_softmax(
    const float* __restrict__ rpool, const float* __restrict__ rlw,
    const float* __restrict__ rlb, float* __restrict__ rw) {
  int t = threadIdx.x;
  __shared__ float logits[2][3];
  for (int b = 0; b < 2; ++b) {
    float p = rpool[b * 64 + t] * (1.0f / 4096.0f);
    for (int e = 0; e < 3; ++e) {
      float v = p * rlw[e * 64 + t];
      for (int off = 32; off; off >>= 1) v += __shfl_xor(v, off);
      if (t == 0) logits[b][e] = v + rlb[e];
    }
  }
  __syncthreads();
  if (t == 0) {
    for (int b = 0; b < 2; ++b) {
      float m = fmaxf(fmaxf(logits[b][0], logits[b][1]), logits[b][2]);
      float e0 = expf(logits[b][0] - m), e1 = expf(logits[b][1] - m),
            e2 = expf(logits[b][2] - m);
      float s = e0 + e1 + e2;
      rw[b * 3 + 0] = e0 / s;
      rw[b * 3 + 1] = e1 / s;
      rw[b * 3 + 2] = e2 / s;
    }
  }
}

// ---------------- fused out-proj weights: WF[e] = fw @ outw[e] ----------------
__global__ __launch_bounds__(256) void k_wfuse(
    const float* __restrict__ fw, const float* __restrict__ outw,
    float* __restrict__ wf) {
  int e = blockIdx.x >> 7;
  int co = blockIdx.x & 127;
  int k = threadIdx.x;
  float acc = 0.f;
  const float* fwr = fw + (size_t)co * 128;
  const float* ob = outw + (size_t)e * 128 * 256 + k;
#pragma unroll 8
  for (int m = 0; m < 128; ++m) acc = fmaf(fwr[m], ob[(size_t)m * 256], acc);
  wf[((size_t)e * 128 + co) * 256 + k] = acc;
}

// ---------------- in-projection GEMM: xr[e,b,l,0:512] ----------------
__global__ __launch_bounds__(256) void k_gemm_in(
    const float* __restrict__ x, const float* __restrict__ inw,
    float* __restrict__ xr) {
  int eb = blockIdx.y;
  int e = eb >> 1, b = eb & 1;
  int lt = blockIdx.x >> 3;
  int jt = blockIdx.x & 7;
  int l0 = lt * 128, j0 = jt * 64;
  __shared__ float xt[16][128];
  __shared__ float wt[16][64];
  int tid = threadIdx.x;
  int jj = (tid & 15) * 4;
  int lr = (tid >> 4) * 8;
  float acc[8][4] = {};
  const float* xb = x + (size_t)b * 128 * 4096;
  const float* wb = inw + (size_t)e * 512 * 128;
  for (int c0 = 0; c0 < 128; c0 += 16) {
    __syncthreads();
#pragma unroll
    for (int i = 0; i < 2; ++i) {
      int f = tid + i * 256;
      int c = f >> 5;
      int lp = (f & 31) * 4;
      float4 v = *(const float4*)(xb + (size_t)(c0 + c) * 4096 + l0 + lp);
      *(float4*)(&xt[c][lp]) = v;
    }
    {
      int j = tid >> 2;
      int kk = (tid & 3) * 4;
      float4 v = *(const float4*)(wb + (size_t)(j0 + j) * 128 + c0 + kk);
      wt[kk + 0][j] = v.x; wt[kk + 1][j] = v.y;
      wt[kk + 2][j] = v.z; wt[kk + 3][j] = v.w;
    }
    __syncthreads();
#pragma unroll
    for (int k = 0; k < 16; ++k) {
      float4 bv = *(const float4*)(&wt[k][jj]);
      float4 a0 = *(const float4*)(&xt[k][lr]);
      float4 a1 = *(const float4*)(&xt[k][lr + 4]);
      float av[8] = {a0.x, a0.y, a0.z, a0.w, a1.x, a1.y, a1.z, a1.w};
#pragma unroll
      for (int i = 0; i < 8; ++i) {
        acc[i][0] = fmaf(av[i], bv.x, acc[i][0]);
        acc[i][1] = fmaf(av[i], bv.y, acc[i][1]);
        acc[i][2] = fmaf(av[i], bv.z, acc[i][2]);
        acc[i][3] = fmaf(av[i], bv.w, acc[i][3]);
      }
    }
  }
  float* out = xr + (size_t)eb * 4096 * 512;
#pragma unroll
  for (int i = 0; i < 8; ++i) {
    float4 v = {acc[i][0], acc[i][1], acc[i][2], acc[i][3]};
    *(float4*)(out + (size_t)(l0 + lr + i) * 512 + j0 + jj) = v;
  }
}

// ---------------- depthwise causal conv1d + silu (16 t per block) ----------------
__global__ __launch_bounds__(256) void k_conv1d(
    const float* __restrict__ xr, const float* __restrict__ cw,
    const float* __restrict__ cb, float* __restrict__ xact) {
  int eb = blockIdx.y;
  int e = eb >> 1;
  int l0 = blockIdx.x * 16;
  int d = threadIdx.x;
  const float* w = cw + (size_t)(e * 256 + d) * 4;
  float w0_ = w[0], w1_ = w[1], w2_ = w[2], w3_ = w[3];
  float bias = cb[e * 256 + d];
  const float* xin = xr + (size_t)eb * 4096 * 512 + d;
  float* xo = xact + (size_t)eb * 4096 * 256 + d;
  float xm3 = (l0 >= 3) ? xin[(size_t)(l0 - 3) * 512] : 0.f;
  float xm2 = (l0 >= 2) ? xin[(size_t)(l0 - 2) * 512] : 0.f;
  float xm1 = (l0 >= 1) ? xin[(size_t)(l0 - 1) * 512] : 0.f;
#pragma unroll
  for (int i = 0; i < 16; ++i) {
    float xc = xin[(size_t)(l0 + i) * 512];
    float v = bias + w0_ * xm3 + w1_ * xm2 + w2_ * xm1 + w3_ * xc;
    xo[(size_t)(l0 + i) * 256] = v / (1.0f + expf(-v));
    xm3 = xm2; xm2 = xm1; xm1 = xc;
  }
}

// ---------------- xproj GEMM: dbl[e,b,l,0:136] ----------------
__global__ __launch_bounds__(256) void k_gemm_xproj(
    const float* __restrict__ xact, const float* __restrict__ xpw,
    float* __restrict__ dbl) {
  int eb = blockIdx.y;
  int e = eb >> 1;
  int lt = blockIdx.x / 3, jt = blockIdx.x % 3;
  int l0 = lt * 128, j0 = jt * 64;
  __shared__ float at[16][128];
  __shared__ float wt[16][64];
  int tid = threadIdx.x;
  int jj = (tid & 15) * 4;
  int lr = (tid >> 4) * 8;
  float acc[8][4] = {};
  const float* ab = xact + (size_t)eb * 4096 * 256;
  const float* wb = xpw + (size_t)e * 136 * 256;
  for (int k0 = 0; k0 < 256; k0 += 16) {
    __syncthreads();
#pragma unroll
    for (int i = 0; i < 2; ++i) {
      int f = tid + i * 256;
      int l = f >> 2, kq = (f & 3) * 4;
      float4 v = *(const float4*)(ab + (size_t)(l0 + l) * 256 + k0 + kq);
      at[kq + 0][l] = v.x; at[kq + 1][l] = v.y;
      at[kq + 2][l] = v.z; at[kq + 3][l] = v.w;
    }
    {
      int j = tid >> 2, kk = (tid & 3) * 4;
      float4 v = {0, 0, 0, 0};
      if (j0 + j < 136)
        v = *(const float4*)(wb + (size_t)(j0 + j) * 256 + k0 + kk);
      wt[kk + 0][j] = v.x; wt[kk + 1][j] = v.y;
      wt[kk + 2][j] = v.z; wt[kk + 3][j] = v.w;
    }
    __syncthreads();
#pragma unroll
    for (int k = 0; k < 16; ++k) {
      float4 bv = *(const float4*)(&wt[k][jj]);
      float4 a0 = *(const float4*)(&at[k][lr]);
      float4 a1 = *(const float4*)(&at[k][lr + 4]);
      float av[8] = {a0.x, a0.y, a0.z, a0.w, a1.x, a1.y, a1.z, a1.w};
#pragma unroll
      for (int i = 0; i < 8; ++i) {
        acc[i][0] = fmaf(av[i], bv.x, acc[i][0]);
        acc[i][1] = fmaf(av[i], bv.y, acc[i][1]);
        acc[i][2] = fmaf(av[i], bv.z, acc[i][2]);
        acc[i][3] = fmaf(av[i], bv.w, acc[i][3]);
      }
    }
  }
  float* ob = dbl + (size_t)eb * 4096 * 136;
  for (int i = 0; i < 8; ++i)
    for (int q = 0; q < 4; ++q) {
      int j = j0 + jj + q;
      if (j < 136) ob[(size_t)(l0 + lr + i) * 136 + j] = acc[i][q];
    }
}

// ---------------- delta pass (32 t per block) ----------------
__global__ __launch_bounds__(256) void k_delta(
    const float* __restrict__ dbl, const float* __restrict__ dtw,
    const float* __restrict__ dtb, const float* __restrict__ xact,
    float* __restrict__ dd) {
  int eb = blockIdx.y;
  int e = eb >> 1;
  int t0 = blockIdx.x * 32;
  int d = threadIdx.x;
  __shared__ float dt8[32][8];
  {
    int f = threadIdx.x;
    if (f < 256) {
      int l = f >> 3, r = f & 7;
      dt8[l][r] = dbl[(size_t)eb * 4096 * 136 + (size_t)(t0 + l) * 136 + r];
    }
  }
  __syncthreads();
  float w[8];
#pragma unroll
  for (int r = 0; r < 8; ++r) w[r] = dtw[(size_t)(e * 256 + d) * 8 + r];
  float bias = dtb[e * 256 + d];
  const float* xa = xact + (size_t)eb * 4096 * 256 + d;
  float4* out = (float4*)dd + (size_t)(eb * 256 + d) * 2048 + (t0 >> 1);
  for (int i = 0; i < 32; i += 2) {
    float v0 = bias, v1 = bias;
#pragma unroll
    for (int r = 0; r < 8; ++r) {
      v0 += dt8[i][r] * w[r];
      v1 += dt8[i + 1][r] * w[r];
    }
    float de0 = fmaxf(v0, 0.f) + log1pf(expf(-fabsf(v0)));
    float de1 = fmaxf(v1, 0.f) + log1pf(expf(-fabsf(v1)));
    float u0 = xa[(size_t)(t0 + i) * 256];
    float u1 = xa[(size_t)(t0 + i + 1) * 256];
    float4 o = {de0, de0 * u0, de1, de1 * u1};
    out[i >> 1] = o;
  }
}

// ---------------- chunked selective scan (R14 structure, NCHUNK=8) ----------------
#define S1STEP(DVX, DVY, ROW)                    \
  {                                              \
    float Bn = sB[cur][ROW][lane];               \
    h = fmaf(EXP2R((DVX)*An2), h, (DVY)*Bn);     \
    sdel += (DVX);                               \
  }
#define S1HALF(R0, R1, R2, R3, ROFF)             \
  {                                              \
    S1STEP(R0.x, R0.y, (ROFF) + 0)               \
    S1STEP(R0.z, R0.w, (ROFF) + 1)               \
    S1STEP(R1.x, R1.y, (ROFF) + 2)               \
    S1STEP(R1.z, R1.w, (ROFF) + 3)               \
    S1STEP(R2.x, R2.y, (ROFF) + 4)               \
    S1STEP(R2.z, R2.w, (ROFF) + 5)               \
    S1STEP(R3.x, R3.y, (ROFF) + 6)               \
    S1STEP(R3.z, R3.w, (ROFF) + 7)               \
  }

// pass 1: per (eb,d,chunk c<7): local scan h=0 -> h_end; prod = exp2(An2*sum(delta))
__global__ __launch_bounds__(256, 6) void k_scan1(
    const float* __restrict__ dbl, const float* __restrict__ dd,
    const float* __restrict__ alog, float* __restrict__ prd,
    float* __restrict__ hend) {
  __shared__ float sB[2][16][64];
  int eb = blockIdx.y;
  int e = eb >> 1;
  int c = blockIdx.x >> 6;
  int dgrp = blockIdx.x & 63;
  int wid = threadIdx.x >> 6, lane = threadIdx.x & 63;
  int d = dgrp * 4 + wid;
  float An2 = -__expf(alog[((size_t)e * 256 + d) * 64 + lane]) * LOG2E;
  const float2* ddp = (const float2*)dd + ((size_t)eb * 256 + d) * 4096;
  {
    uint64_t a = (uint64_t)ddp;
    uint32_t lo = __builtin_amdgcn_readfirstlane((int)(uint32_t)a);
    uint32_t hi = __builtin_amdgcn_readfirstlane((int)(uint32_t)(a >> 32));
    ddp = (const float2*)(((uint64_t)hi << 32) | (uint64_t)lo);
  }
  const float4* dq = (const float4*)ddp;
  const float* dblb = dbl + (size_t)eb * 4096 * 136;
  int t0 = c * TC;
  int qb = t0 >> 1;
  int srow = 4 * wid + (lane >> 4);
  int scol = (lane & 15) * 4;
  float h = 0.f, sdel = 0.f;
  float4 ra0 = dq[qb + 0], ra1 = dq[qb + 1], ra2 = dq[qb + 2],
         ra3 = dq[qb + 3];
  float4 rb0, rb1, rb2, rb3;
  gload_lds16(dblb + (size_t)(t0 + srow) * 136 + 8 + scol, &sB[0][4 * wid][0]);
  __syncthreads();
  for (int sb = 0; sb < 32; ++sb) {
    int cur = sb & 1;
    if (sb + 1 < 32)
      gload_lds16(dblb + (size_t)(t0 + (sb + 1) * 16 + srow) * 136 + 8 + scol,
                  &sB[cur ^ 1][4 * wid][0]);
    int qA = qb + sb * 8;
    rb0 = dq[qA + 4]; rb1 = dq[qA + 5]; rb2 = dq[qA + 6]; rb3 = dq[qA + 7];
    S1HALF(ra0, ra1, ra2, ra3, 0)
    ra0 = dq[qA + 8]; ra1 = dq[qA + 9]; ra2 = dq[qA + 10]; ra3 = dq[qA + 11];
    S1HALF(rb0, rb1, rb2, rb3, 8)
    __syncthreads();
  }
  size_t o = (((size_t)eb * 256 + d) * NCHUNK + c) * 64 + lane;
  prd[o] = EXP2R(An2 * sdel);
  hend[o] = h;
}

// pass 2: sequential combine over chunks -> h_init per chunk
__global__ __launch_bounds__(256) void k_scan2(
    const float* __restrict__ prd, const float* __restrict__ hend,
    float* __restrict__ hinit) {
  int w = blockIdx.x * 4 + (threadIdx.x >> 6);
  int lane = threadIdx.x & 63;
  size_t base = (size_t)w * NCHUNK * 64 + lane;
  float h = 0.f;
  hinit[base] = 0.f;
#pragma unroll
  for (int c = 1; c < NCHUNK; ++c) {
    h = fmaf(prd[base + (c - 1) * 64], h, hend[base + (c - 1) * 64]);
    hinit[base + c * 64] = h;
  }
}

#define S3STEP(DVX, DVY, ROW, JJ)                  \
  {                                                \
    float Bn = sBC[cur][ROW][lane];                \
    float Cn = sBC[cur][ROW][64 + lane];           \
    h = fmaf(EXP2R((DVX)*An2), h, (DVY)*Bn);       \
    P[wid][JJ][lane] = h * Cn;                     \
  }
#define S3HALF(R0, R1, R2, R3, ROFF, TB)           \
  {                                                \
    S3STEP(R0.x, R0.y, (ROFF) + 0, 0)              \
    S3STEP(R0.z, R0.w, (ROFF) + 1, 1)              \
    S3STEP(R1.x, R1.y, (ROFF) + 2, 2)              \
    S3STEP(R1.z, R1.w, (ROFF) + 3, 3)              \
    S3STEP(R2.x, R2.y, (ROFF) + 4, 4)              \
    S3STEP(R2.z, R2.w, (ROFF) + 5, 5)              \
    S3STEP(R3.x, R3.y, (ROFF) + 6, 6)              \
    S3STEP(R3.z, R3.w, (ROFF) + 7, 7)              \
    float acc_ = 0.f;                              \
    _Pragma("unroll")                              \
    for (int k2 = 0; k2 < 8; ++k2)                 \
      acc_ += P[wid][r][q * 8 + k2];               \
    acc_ += __shfl_xor(acc_, 8);                   \
    acc_ += __shfl_xor(acc_, 16);                  \
    acc_ += __shfl_xor(acc_, 32);                  \
    if (lane < 8) yout[(TB) + r] = acc_;           \
  }

// pass 3: local scan from h_init; 16-t B+C staging subblocks (24.7 KB LDS),
// ddp prefetched one 8-t block ahead; per-wave deferred LDS reduce each 8 t.
__global__ __launch_bounds__(256, 6) void k_scan3(
    const float* __restrict__ dbl, const float* __restrict__ dd,
    const float* __restrict__ alog, const float* __restrict__ hinit,
    float* __restrict__ ytr) {
  __shared__ float sBC[2][16][128];
  __shared__ float P[4][8][65];
  int eb = blockIdx.y;
  int e = eb >> 1;
  int c = blockIdx.x >> 6;
  int dgrp = blockIdx.x & 63;
  int wid = threadIdx.x >> 6, lane = threadIdx.x & 63;
  int d = dgrp * 4 + wid;
  float An2 = -__expf(alog[((size_t)e * 256 + d) * 64 + lane]) * LOG2E;
  const float2* ddp = (const float2*)dd + ((size_t)eb * 256 + d) * 4096;
  {
    uint64_t a = (uint64_t)ddp;
    uint32_t lo = __builtin_amdgcn_readfirstlane((int)(uint32_t)a);
    uint32_t hi = __builtin_amdgcn_readfirstlane((int)(uint32_t)(a >> 32));
    ddp = (const float2*)(((uint64_t)hi << 32) | (uint64_t)lo);
  }
  const float4* dq = (const float4*)ddp;
  const float* dblb = dbl + (size_t)eb * 4096 * 136;
  int t0 = c * TC;
  int qb = t0 >> 1;
  int scol = (lane & 31) * 4;
  int srow0 = 4 * wid + (lane >> 5);
  float h = hinit[(((size_t)eb * 256 + d) * NCHUNK + c) * 64 + lane];
  float* yout = ytr + ((size_t)eb * 256 + d) * 4096;
  int r = lane & 7, q = lane >> 3;
  float4 ra0 = dq[qb + 0], ra1 = dq[qb + 1], ra2 = dq[qb + 2],
         ra3 = dq[qb + 3];
  float4 rb0, rb1, rb2, rb3;
  gload_lds16(dblb + (size_t)(t0 + srow0) * 136 + 8 + scol,
              &sBC[0][4 * wid][0]);
  gload_lds16(dblb + (size_t)(t0 + srow0 + 2) * 136 + 8 + scol,
              &sBC[0][4 * wid + 2][0]);
  __syncthreads();
  for (int sb = 0; sb < 32; ++sb) {
    int cur = sb & 1;
    if (sb + 1 < 32) {
      int tN = t0 + (sb + 1) * 16;
      gload_lds16(dblb + (size_t)(tN + srow0) * 136 + 8 + scol,
                  &sBC[cur ^ 1][4 * wid][0]);
      gload_lds16(dblb + (size_t)(tN + srow0 + 2) * 136 + 8 + scol,
                  &sBC[cur ^ 1][4 * wid + 2][0]);
    }
    int qA = qb + sb * 8;
    int tA = t0 + sb * 16;
    rb0 = dq[qA + 4]; rb1 = dq[qA + 5]; rb2 = dq[qA + 6]; rb3 = dq[qA + 7];
    S3HALF(ra0, ra1, ra2, ra3, 0, tA)
    ra0 = dq[qA + 8]; ra1 = dq[qA + 9]; ra2 = dq[qA + 10]; ra3 = dq[qA + 11];
    S3HALF(rb0, rb1, rb2, rb3, 8, tA + 8)
    __syncthreads();
  }
}

// ---------------- y fuse ----------------
__global__ __launch_bounds__(256) void k_yfuse(
    const float* __restrict__ ytr, const float* __restrict__ xact,
    const float* __restrict__ xr, const float* __restrict__ Dw,
    float* __restrict__ yf) {
  int eb = blockIdx.y;
  int e = eb >> 1;
  int dti = blockIdx.x >> 6, tti = blockIdx.x & 63;
  int d0 = dti * 64, t0 = tti * 64;
  __shared__ float sp[64][65];
  __shared__ float sq[64][65];
  int tid = threadIdx.x;
  int j = tid & 63;
  int r0 = tid >> 6;
  float Dj = Dw[e * 256 + d0 + j];
  const float* xab = xact + (size_t)eb * 4096 * 256;
  const float* xrb = xr + (size_t)eb * 4096 * 512;
#pragma unroll
  for (int it = 0; it < 16; ++it) {
    int r = r0 + it * 4;
    float xa = xab[(size_t)(t0 + r) * 256 + d0 + j];
    float rs = xrb[(size_t)(t0 + r) * 512 + 256 + d0 + j];
    float pch = rs / (1.0f + expf(-rs));
    sp[r][j] = pch;
    sq[r][j] = xa * Dj * pch;
  }
  __syncthreads();
#pragma unroll
  for (int it = 0; it < 16; ++it) {
    int ddr = r0 + it * 4;
    size_t idx = ((size_t)eb * 256 + d0 + ddr) * 4096 + t0 + j;
    float y = ytr[idx];
    yf[idx] = y * sp[j][ddr] + sq[j][ddr];
  }
}

// ---------------- fused out-proj + expert-mix + fusion GEMM -> d_out ----------------
// 32x64 tiles: grid (256, 2) = 512 blocks (2/CU; the 64x64 tiling was 1/CU).
__global__ __launch_bounds__(256) void k_gemm_out2(
    const float* __restrict__ yf, const float* __restrict__ wf,
    const float* __restrict__ rw, const float* __restrict__ fb,
    float* __restrict__ out) {
  int b = blockIdx.y;
  int tt = blockIdx.x >> 1;
  int ct = blockIdx.x & 1;
  int t0 = tt * 32, c0 = ct * 64;
  __shared__ float at[16][34];
  __shared__ float wt[16][64];
  int tid = threadIdx.x;
  int c4 = (tid & 15) * 4;
  int t2 = (tid >> 4) * 2;
  float acc[2][4] = {};
  for (int e = 0; e < 3; ++e) {
    float wbe = rw[b * 3 + e];
    const float* ab = yf + (size_t)(e * 2 + b) * 256 * 4096;
    const float* wb = wf + (size_t)e * 128 * 256;
    for (int k0 = 0; k0 < 256; k0 += 16) {
      __syncthreads();
      {
        int f = tid;
        for (int i = 0; i < 2; ++i, f += 256) {
          int t = f & 31, k = f >> 5;
          at[k][t] = ab[(size_t)(k0 + k) * 4096 + t0 + t];
        }
        int jc = tid >> 2, kk = (tid & 3) * 4;
        float4 v = *(const float4*)(wb + (size_t)(c0 + jc) * 256 + k0 + kk);
        wt[kk + 0][jc] = v.x * wbe; wt[kk + 1][jc] = v.y * wbe;
        wt[kk + 2][jc] = v.z * wbe; wt[kk + 3][jc] = v.w * wbe;
      }
      __syncthreads();
#pragma unroll
      for (int k = 0; k < 16; ++k) {
        float4 bv = *(const float4*)(&wt[k][c4]);
        float a0 = at[k][t2], a1 = at[k][t2 + 1];
        acc[0][0] = fmaf(a0, bv.x, acc[0][0]);
        acc[0][1] = fmaf(a0, bv.y, acc[0][1]);
        acc[0][2] = fmaf(a0, bv.z, acc[0][2]);
        acc[0][3] = fmaf(a0, bv.w, acc[0][3]);
        acc[1][0] = fmaf(a1, bv.x, acc[1][0]);
        acc[1][1] = fmaf(a1, bv.y, acc[1][1]);
        acc[1][2] = fmaf(a1, bv.z, acc[1][2]);
        acc[1][3] = fmaf(a1, bv.w, acc[1][3]);
      }
    }
  }
#pragma unroll
  for (int o = 0; o < 4; ++o) {
    float bias = fb[c0 + c4 + o];
    float2 v = {acc[0][o] + bias, acc[1][o] + bias};
    *(float2*)(out + ((size_t)(b * 128 + c0 + c4 + o)) * 4096 + t0 + t2) = v;
  }
}

extern "C" void kernel_launch(void* const* d_in, const int* in_sizes, int n_in,
                              void* d_out, int out_size, void* d_ws,
                              size_t ws_size, hipStream_t stream) {
  const float* x    = (const float*)d_in[0];
  const float* inw  = (const float*)d_in[1];
  const float* cw   = (const float*)d_in[2];
  const float* cb   = (const float*)d_in[3];
  const float* xpw  = (const float*)d_in[4];
  const float* dtw  = (const float*)d_in[5];
  const float* dtb  = (const float*)d_in[6];
  const float* alog = (const float*)d_in[7];
  const float* Dw   = (const float*)d_in[8];
  const float* outw = (const float*)d_in[9];
  const float* rcw  = (const float*)d_in[10];
  const float* rcb  = (const float*)d_in[11];
  const float* rlw  = (const float*)d_in[12];
  const float* rlb  = (const float*)d_in[13];
  const float* fw   = (const float*)d_in[14];
  const float* fb   = (const float*)d_in[15];

  float* ws = (float*)d_ws;
  float* XR    = ws;                 // 12,582,912
  float* XACT  = ws + 12582912;      // 6,291,456
  float* DBL   = ws + 18874368;      // 3,342,336
  float* DD    = ws + 22216704;      // 12,582,912 (also reused as YF)
  float* YTR   = ws + 34799616;      // 6,291,456
  float* MIX   = ws + 41091072;      // 1,048,576 (scratch region)
  float* RPOOL = ws + 42139648;      // 128
  float* RW    = ws + 42139776;      // 8
  float* YF    = DD;
  float* PRD   = YTR;
  float* HEND  = YTR + 786432;
  float* HINIT = MIX;
  float* WF    = MIX + 786432;

  if (ws_size < (size_t)42139784 * sizeof(float)) return;

  hipMemsetAsync(RPOOL, 0, 128 * sizeof(float), stream);
  k_router_conv<<<512, 256, 0, stream>>>(x, rcw, rcb, RPOOL);
  k_router_softmax<<<1, 64, 0, stream>>>(RPOOL, rlw, rlb, RW);
  k_wfuse<<<384, 256, 0, stream>>>(fw, outw, WF);
  k_gemm_in<<<dim3(256, 6), 256, 0, stream>>>(x, inw, XR);
  k_conv1d<<<dim3(256, 6), 256, 0, stream>>>(XR, cw, cb, XACT);
  k_gemm_xproj<<<dim3(96, 6), 256, 0, stream>>>(XACT, xpw, DBL);
  k_delta<<<dim3(128, 6), 256, 0, stream>>>(DBL, dtw, dtb, XACT, DD);
  k_scan1<<<dim3(64 * 7, 6), 256, 0, stream>>>(DBL, DD, alog, PRD, HEND);
  k_scan2<<<384, 256, 0, stream>>>(PRD, HEND, HINIT);
  k_scan3<<<dim3(64 * NCHUNK, 6), 256, 0, stream>>>(DBL, DD, alog, HINIT, YTR);
  k_yfuse<<<dim3(256, 6), 256, 0, stream>>>(YTR, XACT, XR, Dw, YF);
  k_gemm_out2<<<dim3(256, 2), 256, 0, stream>>>(YF, WF, RW, fb,
                                                (float*)d_out);
}

// Round 17
// 566.836 us; speedup vs baseline: 1.0250x; 1.0161x over previous
//
#include <hip/hip_runtime.h>
#include <math.h>
#include <stdint.h>

#define LSEQ 4096
#define NCHUNK 8
#define TC 512  // LSEQ / NCHUNK

#define AS1 __attribute__((address_space(1)))
#define AS3 __attribute__((address_space(3)))
__device__ __forceinline__ void gload_lds16(const void* g, void* l) {
  __builtin_amdgcn_global_load_lds((const AS1 unsigned int*)g,
                                   (AS3 unsigned int*)l, 16, 0, 0);
}

// raw v_exp_f32 (exp2). libm exp2f carries denorm-range fixup (~6 VALU);
// results below 2^-126 flush to zero, irrelevant at our 2.4e-6 threshold.
#define EXP2R(X) __builtin_amdgcn_exp2f(X)
#define LOG2E 1.44269504f

// ---------------- router: conv3x3 + relu + pooled sums ----------------
__global__ __launch_bounds__(256) void k_router_conv(
    const float* __restrict__ x, const float* __restrict__ rcw,
    const float* __restrict__ rcb, float* __restrict__ rpool) {
  int bid = blockIdx.x;
  int ocq = bid & 3;
  int h = (bid >> 2) & 63;
  int b = bid >> 8;
  __shared__ float xs[16][3][66];
  __shared__ float wl[16][145];
  int tid = threadIdx.x;
  int ocl = tid & 15;
  int oc = ocq * 16 + ocl;
  int w0 = (tid >> 4) * 4;
  if (tid < 96) {
    int ic = tid / 6, rr = tid % 6;
    int row = rr >> 1, edge = (rr & 1) ? 65 : 0;
    xs[ic][row][edge] = 0.f;
  }
  float acc[4] = {};
  for (int cc = 0; cc < 8; ++cc) {
    __syncthreads();
#pragma unroll
    for (int i = 0; i < 12; ++i) {
      int f = tid + i * 256;
      int ic = f / 192, rem = f % 192;
      int row = rem / 64, w = rem & 63;
      int hh = h - 1 + row;
      float v = 0.f;
      if (hh >= 0 && hh < 64)
        v = x[((size_t)(b * 128 + cc * 16 + ic) * 64 + hh) * 64 + w];
      xs[ic][row][w + 1] = v;
    }
    for (int f = tid; f < 2304; f += 256) {
      int o = f / 144, r = f % 144;
      wl[o][r] = rcw[(size_t)(ocq * 16 + o) * 1152 + cc * 144 + r];
    }
    __syncthreads();
    for (int ic = 0; ic < 16; ++ic) {
#pragma unroll
      for (int kh = 0; kh < 3; ++kh) {
        float xv[6];
#pragma unroll
        for (int j = 0; j < 6; ++j) xv[j] = xs[ic][kh][w0 + j];
        float w_0 = wl[ocl][ic * 9 + kh * 3 + 0];
        float w_1 = wl[ocl][ic * 9 + kh * 3 + 1];
        float w_2 = wl[ocl][ic * 9 + kh * 3 + 2];
#pragma unroll
        for (int i = 0; i < 4; ++i)
          acc[i] += w_0 * xv[i] + w_1 * xv[i + 1] + w_2 * xv[i + 2];
      }
    }
  }
  float cbv = rcb[oc];
  float t = 0.f;
#pragma unroll
  for (int i = 0; i < 4; ++i) t += fmaxf(acc[i] + cbv, 0.f);
  t += __shfl_xor(t, 16);
  t += __shfl_xor(t, 32);
  if ((tid & 63) < 16) atomicAdd(rpool + b * 64 + oc, t);
}

__global__ __launch_bounds__(64) void k_router_softmax(
    const float* __restrict__ rpool, const float* __restrict__ rlw,
    const float* __restrict__ rlb, float* __restrict__ rw) {
  int t = threadIdx.x;
  __shared__ float logits[2][3];
  for (int b = 0; b < 2; ++b) {
    float p = rpool[b * 64 + t] * (1.0f / 4096.0f);
    for (int e = 0; e < 3; ++e) {
      float v = p * rlw[e * 64 + t];
      for (int off = 32; off; off >>= 1) v += __shfl_xor(v, off);
      if (t == 0) logits[b][e] = v + rlb[e];
    }
  }
  __syncthreads();
  if (t == 0) {
    for (int b = 0; b < 2; ++b) {
      float m = fmaxf(fmaxf(logits[b][0], logits[b][1]), logits[b][2]);
      float e0 = expf(logits[b][0] - m), e1 = expf(logits[b][1] - m),
            e2 = expf(logits[b][2] - m);
      float s = e0 + e1 + e2;
      rw[b * 3 + 0] = e0 / s;
      rw[b * 3 + 1] = e1 / s;
      rw[b * 3 + 2] = e2 / s;
    }
  }
}

// ---------------- fused out-proj weights: WF[e] = fw @ outw[e] ----------------
__global__ __launch_bounds__(256) void k_wfuse(
    const float* __restrict__ fw, const float* __restrict__ outw,
    float* __restrict__ wf) {
  int e = blockIdx.x >> 7;
  int co = blockIdx.x & 127;
  int k = threadIdx.x;
  float acc = 0.f;
  const float* fwr = fw + (size_t)co * 128;
  const float* ob = outw + (size_t)e * 128 * 256 + k;
#pragma unroll 8
  for (int m = 0; m < 128; ++m) acc = fmaf(fwr[m], ob[(size_t)m * 256], acc);
  wf[((size_t)e * 128 + co) * 256 + k] = acc;
}

// ---------------- in-projection GEMM: xr[e,b,l,0:512] ----------------
__global__ __launch_bounds__(256) void k_gemm_in(
    const float* __restrict__ x, const float* __restrict__ inw,
    float* __restrict__ xr) {
  int eb = blockIdx.y;
  int e = eb >> 1, b = eb & 1;
  int lt = blockIdx.x >> 3;
  int jt = blockIdx.x & 7;
  int l0 = lt * 128, j0 = jt * 64;
  __shared__ float xt[16][128];
  __shared__ float wt[16][64];
  int tid = threadIdx.x;
  int jj = (tid & 15) * 4;
  int lr = (tid >> 4) * 8;
  float acc[8][4] = {};
  const float* xb = x + (size_t)b * 128 * 4096;
  const float* wb = inw + (size_t)e * 512 * 128;
  for (int c0 = 0; c0 < 128; c0 += 16) {
    __syncthreads();
#pragma unroll
    for (int i = 0; i < 2; ++i) {
      int f = tid + i * 256;
      int c = f >> 5;
      int lp = (f & 31) * 4;
      float4 v = *(const float4*)(xb + (size_t)(c0 + c) * 4096 + l0 + lp);
      *(float4*)(&xt[c][lp]) = v;
    }
    {
      int j = tid >> 2;
      int kk = (tid & 3) * 4;
      float4 v = *(const float4*)(wb + (size_t)(j0 + j) * 128 + c0 + kk);
      wt[kk + 0][j] = v.x; wt[kk + 1][j] = v.y;
      wt[kk + 2][j] = v.z; wt[kk + 3][j] = v.w;
    }
    __syncthreads();
#pragma unroll
    for (int k = 0; k < 16; ++k) {
      float4 bv = *(const float4*)(&wt[k][jj]);
      float4 a0 = *(const float4*)(&xt[k][lr]);
      float4 a1 = *(const float4*)(&xt[k][lr + 4]);
      float av[8] = {a0.x, a0.y, a0.z, a0.w, a1.x, a1.y, a1.z, a1.w};
#pragma unroll
      for (int i = 0; i < 8; ++i) {
        acc[i][0] = fmaf(av[i], bv.x, acc[i][0]);
        acc[i][1] = fmaf(av[i], bv.y, acc[i][1]);
        acc[i][2] = fmaf(av[i], bv.z, acc[i][2]);
        acc[i][3] = fmaf(av[i], bv.w, acc[i][3]);
      }
    }
  }
  float* out = xr + (size_t)eb * 4096 * 512;
#pragma unroll
  for (int i = 0; i < 8; ++i) {
    float4 v = {acc[i][0], acc[i][1], acc[i][2], acc[i][3]};
    *(float4*)(out + (size_t)(l0 + lr + i) * 512 + j0 + jj) = v;
  }
}

// ---------------- depthwise causal conv1d + silu (16 t per block) ----------------
__global__ __launch_bounds__(256) void k_conv1d(
    const float* __restrict__ xr, const float* __restrict__ cw,
    const float* __restrict__ cb, float* __restrict__ xact) {
  int eb = blockIdx.y;
  int e = eb >> 1;
  int l0 = blockIdx.x * 16;
  int d = threadIdx.x;
  const float* w = cw + (size_t)(e * 256 + d) * 4;
  float w0_ = w[0], w1_ = w[1], w2_ = w[2], w3_ = w[3];
  float bias = cb[e * 256 + d];
  const float* xin = xr + (size_t)eb * 4096 * 512 + d;
  float* xo = xact + (size_t)eb * 4096 * 256 + d;
  float xm3 = (l0 >= 3) ? xin[(size_t)(l0 - 3) * 512] : 0.f;
  float xm2 = (l0 >= 2) ? xin[(size_t)(l0 - 2) * 512] : 0.f;
  float xm1 = (l0 >= 1) ? xin[(size_t)(l0 - 1) * 512] : 0.f;
#pragma unroll
  for (int i = 0; i < 16; ++i) {
    float xc = xin[(size_t)(l0 + i) * 512];
    float v = bias + w0_ * xm3 + w1_ * xm2 + w2_ * xm1 + w3_ * xc;
    xo[(size_t)(l0 + i) * 256] = v / (1.0f + expf(-v));
    xm3 = xm2; xm2 = xm1; xm1 = xc;
  }
}

// ---------------- xproj GEMM: dbl[e,b,l,0:136] ----------------
__global__ __launch_bounds__(256) void k_gemm_xproj(
    const float* __restrict__ xact, const float* __restrict__ xpw,
    float* __restrict__ dbl) {
  int eb = blockIdx.y;
  int e = eb >> 1;
  int lt = blockIdx.x / 3, jt = blockIdx.x % 3;
  int l0 = lt * 128, j0 = jt * 64;
  __shared__ float at[16][128];
  __shared__ float wt[16][64];
  int tid = threadIdx.x;
  int jj = (tid & 15) * 4;
  int lr = (tid >> 4) * 8;
  float acc[8][4] = {};
  const float* ab = xact + (size_t)eb * 4096 * 256;
  const float* wb = xpw + (size_t)e * 136 * 256;
  for (int k0 = 0; k0 < 256; k0 += 16) {
    __syncthreads();
#pragma unroll
    for (int i = 0; i < 2; ++i) {
      int f = tid + i * 256;
      int l = f >> 2, kq = (f & 3) * 4;
      float4 v = *(const float4*)(ab + (size_t)(l0 + l) * 256 + k0 + kq);
      at[kq + 0][l] = v.x; at[kq + 1][l] = v.y;
      at[kq + 2][l] = v.z; at[kq + 3][l] = v.w;
    }
    {
      int j = tid >> 2, kk = (tid & 3) * 4;
      float4 v = {0, 0, 0, 0};
      if (j0 + j < 136)
        v = *(const float4*)(wb + (size_t)(j0 + j) * 256 + k0 + kk);
      wt[kk + 0][j] = v.x; wt[kk + 1][j] = v.y;
      wt[kk + 2][j] = v.z; wt[kk + 3][j] = v.w;
    }
    __syncthreads();
#pragma unroll
    for (int k = 0; k < 16; ++k) {
      float4 bv = *(const float4*)(&wt[k][jj]);
      float4 a0 = *(const float4*)(&at[k][lr]);
      float4 a1 = *(const float4*)(&at[k][lr + 4]);
      float av[8] = {a0.x, a0.y, a0.z, a0.w, a1.x, a1.y, a1.z, a1.w};
#pragma unroll
      for (int i = 0; i < 8; ++i) {
        acc[i][0] = fmaf(av[i], bv.x, acc[i][0]);
        acc[i][1] = fmaf(av[i], bv.y, acc[i][1]);
        acc[i][2] = fmaf(av[i], bv.z, acc[i][2]);
        acc[i][3] = fmaf(av[i], bv.w, acc[i][3]);
      }
    }
  }
  float* ob = dbl + (size_t)eb * 4096 * 136;
  for (int i = 0; i < 8; ++i)
    for (int q = 0; q < 4; ++q) {
      int j = j0 + jj + q;
      if (j < 136) ob[(size_t)(l0 + lr + i) * 136 + j] = acc[i][q];
    }
}

// ---------------- delta pass (64 t per block) ----------------
__global__ __launch_bounds__(256) void k_delta(
    const float* __restrict__ dbl, const float* __restrict__ dtw,
    const float* __restrict__ dtb, const float* __restrict__ xact,
    float* __restrict__ dd) {
  int eb = blockIdx.y;
  int e = eb >> 1;
  int t0 = blockIdx.x * 64;
  int d = threadIdx.x;
  __shared__ float dt8[64][8];
  {
    int f = threadIdx.x;
    for (int i = 0; i < 2; ++i, f += 256) {
      int l = f >> 3, r = f & 7;
      dt8[l][r] = dbl[(size_t)eb * 4096 * 136 + (size_t)(t0 + l) * 136 + r];
    }
  }
  __syncthreads();
  float w[8];
#pragma unroll
  for (int r = 0; r < 8; ++r) w[r] = dtw[(size_t)(e * 256 + d) * 8 + r];
  float bias = dtb[e * 256 + d];
  const float* xa = xact + (size_t)eb * 4096 * 256 + d;
  float4* out = (float4*)dd + (size_t)(eb * 256 + d) * 2048 + (t0 >> 1);
  for (int i = 0; i < 64; i += 2) {
    float v0 = bias, v1 = bias;
#pragma unroll
    for (int r = 0; r < 8; ++r) {
      v0 += dt8[i][r] * w[r];
      v1 += dt8[i + 1][r] * w[r];
    }
    float de0 = fmaxf(v0, 0.f) + log1pf(expf(-fabsf(v0)));
    float de1 = fmaxf(v1, 0.f) + log1pf(expf(-fabsf(v1)));
    float u0 = xa[(size_t)(t0 + i) * 256];
    float u1 = xa[(size_t)(t0 + i + 1) * 256];
    float4 o = {de0, de0 * u0, de1, de1 * u1};
    out[i >> 1] = o;
  }
}

// ---------------- chunked selective scan (R11 structure) ----------------
#define S1STEP(DVX, DVY, ROW)                    \
  {                                              \
    float Bn = sB[cur][ROW][lane];               \
    h = fmaf(EXP2R((DVX)*An2), h, (DVY)*Bn);     \
    sdel += (DVX);                               \
  }
#define S1HALF(R0, R1, R2, R3, ROFF)             \
  {                                              \
    S1STEP(R0.x, R0.y, (ROFF) + 0)               \
    S1STEP(R0.z, R0.w, (ROFF) + 1)               \
    S1STEP(R1.x, R1.y, (ROFF) + 2)               \
    S1STEP(R1.z, R1.w, (ROFF) + 3)               \
    S1STEP(R2.x, R2.y, (ROFF) + 4)               \
    S1STEP(R2.z, R2.w, (ROFF) + 5)               \
    S1STEP(R3.x, R3.y, (ROFF) + 6)               \
    S1STEP(R3.z, R3.w, (ROFF) + 7)               \
  }

// pass 1: per (eb,d,chunk c<7): local scan h=0 -> h_end; prod = exp2(An2*sum(delta))
__global__ __launch_bounds__(256, 6) void k_scan1(
    const float* __restrict__ dbl, const float* __restrict__ dd,
    const float* __restrict__ alog, float* __restrict__ prd,
    float* __restrict__ hend) {
  __shared__ float sB[2][16][64];
  int eb = blockIdx.y;
  int e = eb >> 1;
  int c = blockIdx.x >> 6;
  int dgrp = blockIdx.x & 63;
  int wid = threadIdx.x >> 6, lane = threadIdx.x & 63;
  int d = dgrp * 4 + wid;
  float An2 = -__expf(alog[((size_t)e * 256 + d) * 64 + lane]) * LOG2E;
  const float2* ddp = (const float2*)dd + ((size_t)eb * 256 + d) * 4096;
  {
    uint64_t a = (uint64_t)ddp;
    uint32_t lo = __builtin_amdgcn_readfirstlane((int)(uint32_t)a);
    uint32_t hi = __builtin_amdgcn_readfirstlane((int)(uint32_t)(a >> 32));
    ddp = (const float2*)(((uint64_t)hi << 32) | (uint64_t)lo);
  }
  const float4* dq = (const float4*)ddp;
  const float* dblb = dbl + (size_t)eb * 4096 * 136;
  int t0 = c * TC;
  int qb = t0 >> 1;
  int srow = 4 * wid + (lane >> 4);
  int scol = (lane & 15) * 4;
  float h = 0.f, sdel = 0.f;
  float4 ra0 = dq[qb + 0], ra1 = dq[qb + 1], ra2 = dq[qb + 2],
         ra3 = dq[qb + 3];
  float4 rb0, rb1, rb2, rb3;
  gload_lds16(dblb + (size_t)(t0 + srow) * 136 + 8 + scol, &sB[0][4 * wid][0]);
  __syncthreads();
  for (int sb = 0; sb < 32; ++sb) {
    int cur = sb & 1;
    if (sb + 1 < 32)
      gload_lds16(dblb + (size_t)(t0 + (sb + 1) * 16 + srow) * 136 + 8 + scol,
                  &sB[cur ^ 1][4 * wid][0]);
    int qA = qb + sb * 8;
    rb0 = dq[qA + 4]; rb1 = dq[qA + 5]; rb2 = dq[qA + 6]; rb3 = dq[qA + 7];
    S1HALF(ra0, ra1, ra2, ra3, 0)
    ra0 = dq[qA + 8]; ra1 = dq[qA + 9]; ra2 = dq[qA + 10]; ra3 = dq[qA + 11];
    S1HALF(rb0, rb1, rb2, rb3, 8)
    __syncthreads();
  }
  size_t o = (((size_t)eb * 256 + d) * NCHUNK + c) * 64 + lane;
  prd[o] = EXP2R(An2 * sdel);
  hend[o] = h;
}

// pass 2: sequential combine over chunks -> h_init per chunk
__global__ __launch_bounds__(256) void k_scan2(
    const float* __restrict__ prd, const float* __restrict__ hend,
    float* __restrict__ hinit) {
  int w = blockIdx.x * 4 + (threadIdx.x >> 6);
  int lane = threadIdx.x & 63;
  size_t base = (size_t)w * NCHUNK * 64 + lane;
  float h = 0.f;
  hinit[base] = 0.f;
#pragma unroll
  for (int c = 1; c < NCHUNK; ++c) {
    h = fmaf(prd[base + (c - 1) * 64], h, hend[base + (c - 1) * 64]);
    hinit[base + c * 64] = h;
  }
}

#define S3STEP(DVX, DVY, ROW, JJ)                  \
  {                                                \
    float Bn = sBC[cur][ROW][lane];                \
    float Cn = sBC[cur][ROW][64 + lane];           \
    h = fmaf(EXP2R((DVX)*An2), h, (DVY)*Bn);       \
    P[wid][JJ][lane] = h * Cn;                     \
  }
#define S3HALF(R0, R1, R2, R3, ROFF, TB)           \
  {                                                \
    S3STEP(R0.x, R0.y, (ROFF) + 0, 0)              \
    S3STEP(R0.z, R0.w, (ROFF) + 1, 1)              \
    S3STEP(R1.x, R1.y, (ROFF) + 2, 2)              \
    S3STEP(R1.z, R1.w, (ROFF) + 3, 3)              \
    S3STEP(R2.x, R2.y, (ROFF) + 4, 4)              \
    S3STEP(R2.z, R2.w, (ROFF) + 5, 5)              \
    S3STEP(R3.x, R3.y, (ROFF) + 6, 6)              \
    S3STEP(R3.z, R3.w, (ROFF) + 7, 7)              \
    float acc_ = 0.f;                              \
    _Pragma("unroll")                              \
    for (int k2 = 0; k2 < 8; ++k2)                 \
      acc_ += P[wid][r][q * 8 + k2];               \
    acc_ += __shfl_xor(acc_, 8);                   \
    acc_ += __shfl_xor(acc_, 16);                  \
    acc_ += __shfl_xor(acc_, 32);                  \
    if (lane < 8) yout[(TB) + r] = acc_;           \
  }

// pass 3: local scan from h_init; 16-t B+C staging subblocks (24.7 KB LDS),
// ddp prefetched one 8-t block ahead; per-wave deferred LDS reduce each 8 t.
__global__ __launch_bounds__(256, 6) void k_scan3(
    const float* __restrict__ dbl, const float* __restrict__ dd,
    const float* __restrict__ alog, const float* __restrict__ hinit,
    float* __restrict__ ytr) {
  __shared__ float sBC[2][16][128];
  __shared__ float P[4][8][65];
  int eb = blockIdx.y;
  int e = eb >> 1;
  int c = blockIdx.x >> 6;
  int dgrp = blockIdx.x & 63;
  int wid = threadIdx.x >> 6, lane = threadIdx.x & 63;
  int d = dgrp * 4 + wid;
  float An2 = -__expf(alog[((size_t)e * 256 + d) * 64 + lane]) * LOG2E;
  const float2* ddp = (const float2*)dd + ((size_t)eb * 256 + d) * 4096;
  {
    uint64_t a = (uint64_t)ddp;
    uint32_t lo = __builtin_amdgcn_readfirstlane((int)(uint32_t)a);
    uint32_t hi = __builtin_amdgcn_readfirstlane((int)(uint32_t)(a >> 32));
    ddp = (const float2*)(((uint64_t)hi << 32) | (uint64_t)lo);
  }
  const float4* dq = (const float4*)ddp;
  const float* dblb = dbl + (size_t)eb * 4096 * 136;
  int t0 = c * TC;
  int qb = t0 >> 1;
  int scol = (lane & 31) * 4;
  int srow0 = 4 * wid + (lane >> 5);
  float h = hinit[(((size_t)eb * 256 + d) * NCHUNK + c) * 64 + lane];
  float* yout = ytr + ((size_t)eb * 256 + d) * 4096;
  int r = lane & 7, q = lane >> 3;
  float4 ra0 = dq[qb + 0], ra1 = dq[qb + 1], ra2 = dq[qb + 2],
         ra3 = dq[qb + 3];
  float4 rb0, rb1, rb2, rb3;
  gload_lds16(dblb + (size_t)(t0 + srow0) * 136 + 8 + scol,
              &sBC[0][4 * wid][0]);
  gload_lds16(dblb + (size_t)(t0 + srow0 + 2) * 136 + 8 + scol,
              &sBC[0][4 * wid + 2][0]);
  __syncthreads();
  for (int sb = 0; sb < 32; ++sb) {
    int cur = sb & 1;
    if (sb + 1 < 32) {
      int tN = t0 + (sb + 1) * 16;
      gload_lds16(dblb + (size_t)(tN + srow0) * 136 + 8 + scol,
                  &sBC[cur ^ 1][4 * wid][0]);
      gload_lds16(dblb + (size_t)(tN + srow0 + 2) * 136 + 8 + scol,
                  &sBC[cur ^ 1][4 * wid + 2][0]);
    }
    int qA = qb + sb * 8;
    int tA = t0 + sb * 16;
    rb0 = dq[qA + 4]; rb1 = dq[qA + 5]; rb2 = dq[qA + 6]; rb3 = dq[qA + 7];
    S3HALF(ra0, ra1, ra2, ra3, 0, tA)
    ra0 = dq[qA + 8]; ra1 = dq[qA + 9]; ra2 = dq[qA + 10]; ra3 = dq[qA + 11];
    S3HALF(rb0, rb1, rb2, rb3, 8, tA + 8)
    __syncthreads();
  }
}

// ---------------- y fuse ----------------
__global__ __launch_bounds__(256) void k_yfuse(
    const float* __restrict__ ytr, const float* __restrict__ xact,
    const float* __restrict__ xr, const float* __restrict__ Dw,
    float* __restrict__ yf) {
  int eb = blockIdx.y;
  int e = eb >> 1;
  int dti = blockIdx.x >> 6, tti = blockIdx.x & 63;
  int d0 = dti * 64, t0 = tti * 64;
  __shared__ float sp[64][65];
  __shared__ float sq[64][65];
  int tid = threadIdx.x;
  int j = tid & 63;
  int r0 = tid >> 6;
  float Dj = Dw[e * 256 + d0 + j];
  const float* xab = xact + (size_t)eb * 4096 * 256;
  const float* xrb = xr + (size_t)eb * 4096 * 512;
#pragma unroll
  for (int it = 0; it < 16; ++it) {
    int r = r0 + it * 4;
    float xa = xab[(size_t)(t0 + r) * 256 + d0 + j];
    float rs = xrb[(size_t)(t0 + r) * 512 + 256 + d0 + j];
    float pch = rs / (1.0f + expf(-rs));
    sp[r][j] = pch;
    sq[r][j] = xa * Dj * pch;
  }
  __syncthreads();
#pragma unroll
  for (int it = 0; it < 16; ++it) {
    int ddr = r0 + it * 4;
    size_t idx = ((size_t)eb * 256 + d0 + ddr) * 4096 + t0 + j;
    float y = ytr[idx];
    yf[idx] = y * sp[j][ddr] + sq[j][ddr];
  }
}

// ---------------- fused out-proj + expert-mix + fusion GEMM -> d_out ----------------
__global__ __launch_bounds__(256) void k_gemm_out2(
    const float* __restrict__ yf, const float* __restrict__ wf,
    const float* __restrict__ rw, const float* __restrict__ fb,
    float* __restrict__ out) {
  int b = blockIdx.y;
  int tt = blockIdx.x >> 1;
  int ct = blockIdx.x & 1;
  int t0 = tt * 64, c0 = ct * 64;
  __shared__ float at[16][66];
  __shared__ float wt[16][64];
  int tid = threadIdx.x;
  int co4 = (tid & 15) * 4;
  int t4 = (tid >> 4) * 4;
  float acc[4][4] = {};
  for (int e = 0; e < 3; ++e) {
    float wbe = rw[b * 3 + e];
    const float* ab = yf + (size_t)(e * 2 + b) * 256 * 4096;
    const float* wb = wf + (size_t)e * 128 * 256;
    for (int k0 = 0; k0 < 256; k0 += 16) {
      __syncthreads();
      {
#pragma unroll
        for (int i = 0; i < 4; ++i) {
          int f = tid + i * 256;
          int t = f & 63, k = f >> 6;
          at[k][t] = ab[(size_t)(k0 + k) * 4096 + t0 + t];
        }
        int jc = tid >> 2, kk = (tid & 3) * 4;
        float4 v = *(const float4*)(wb + (size_t)(c0 + jc) * 256 + k0 + kk);
        wt[kk + 0][jc] = v.x * wbe; wt[kk + 1][jc] = v.y * wbe;
        wt[kk + 2][jc] = v.z * wbe; wt[kk + 3][jc] = v.w * wbe;
      }
      __syncthreads();
#pragma unroll
      for (int k = 0; k < 16; ++k) {
        float4 bv = *(const float4*)(&wt[k][co4]);
        float4 av = *(const float4*)(&at[k][t4]);
        float a_[4] = {av.x, av.y, av.z, av.w};
#pragma unroll
        for (int i = 0; i < 4; ++i) {
          acc[i][0] = fmaf(a_[i], bv.x, acc[i][0]);
          acc[i][1] = fmaf(a_[i], bv.y, acc[i][1]);
          acc[i][2] = fmaf(a_[i], bv.z, acc[i][2]);
          acc[i][3] = fmaf(a_[i], bv.w, acc[i][3]);
        }
      }
    }
  }
#pragma unroll
  for (int o = 0; o < 4; ++o) {
    float bias = fb[c0 + co4 + o];
    float4 v = {acc[0][o] + bias, acc[1][o] + bias, acc[2][o] + bias,
                acc[3][o] + bias};
    *(float4*)(out + ((size_t)(b * 128 + c0 + co4 + o)) * 4096 + t0 + t4) = v;
  }
}

extern "C" void kernel_launch(void* const* d_in, const int* in_sizes, int n_in,
                              void* d_out, int out_size, void* d_ws,
                              size_t ws_size, hipStream_t stream) {
  const float* x    = (const float*)d_in[0];
  const float* inw  = (const float*)d_in[1];
  const float* cw   = (const float*)d_in[2];
  const float* cb   = (const float*)d_in[3];
  const float* xpw  = (const float*)d_in[4];
  const float* dtw  = (const float*)d_in[5];
  const float* dtb  = (const float*)d_in[6];
  const float* alog = (const float*)d_in[7];
  const float* Dw   = (const float*)d_in[8];
  const float* outw = (const float*)d_in[9];
  const float* rcw  = (const float*)d_in[10];
  const float* rcb  = (const float*)d_in[11];
  const float* rlw  = (const float*)d_in[12];
  const float* rlb  = (const float*)d_in[13];
  const float* fw   = (const float*)d_in[14];
  const float* fb   = (const float*)d_in[15];

  float* ws = (float*)d_ws;
  float* XR    = ws;                 // 12,582,912
  float* XACT  = ws + 12582912;      // 6,291,456
  float* DBL   = ws + 18874368;      // 3,342,336
  float* DD    = ws + 22216704;      // 12,582,912 (also reused as YF)
  float* YTR   = ws + 34799616;      // 6,291,456
  float* MIX   = ws + 41091072;      // 1,048,576 (scratch region)
  float* RPOOL = ws + 42139648;      // 128
  float* RW    = ws + 42139776;      // 8
  float* YF    = DD;
  float* PRD   = YTR;
  float* HEND  = YTR + 786432;
  float* HINIT = MIX;
  float* WF    = MIX + 786432;

  if (ws_size < (size_t)42139784 * sizeof(float)) return;

  hipMemsetAsync(RPOOL, 0, 128 * sizeof(float), stream);
  k_router_conv<<<512, 256, 0, stream>>>(x, rcw, rcb, RPOOL);
  k_router_softmax<<<1, 64, 0, stream>>>(RPOOL, rlw, rlb, RW);
  k_wfuse<<<384, 256, 0, stream>>>(fw, outw, WF);
  k_gemm_in<<<dim3(256, 6), 256, 0, stream>>>(x, inw, XR);
  k_conv1d<<<dim3(256, 6), 256, 0, stream>>>(XR, cw, cb, XACT);
  k_gemm_xproj<<<dim3(96, 6), 256, 0, stream>>>(XACT, xpw, DBL);
  k_delta<<<dim3(64, 6), 256, 0, stream>>>(DBL, dtw, dtb, XACT, DD);
  k_scan1<<<dim3(64 * 7, 6), 256, 0, stream>>>(DBL, DD, alog, PRD, HEND);
  k_scan2<<<384, 256, 0, stream>>>(PRD, HEND, HINIT);
  k_scan3<<<dim3(64 * NCHUNK, 6), 256, 0, stream>>>(DBL, DD, alog, HINIT, YTR);
  k_yfuse<<<dim3(256, 6), 256, 0, stream>>>(YTR, XACT, XR, Dw, YF);
  k_gemm_out2<<<dim3(128, 2), 256, 0, stream>>>(YF, WF, RW, fb, (float*)d_out);
}